// Round 13
// baseline (50.107 us; speedup 1.0000x reference)
//
#include <hip/hip_runtime.h>

#pragma clang fp contract(off)

#define HH 96
#define WW 96
#define KK 16
#define MM 2
#define NF 512            // M * Fm
#define NV 512            // M * V
#define NPIX (HH*WW)      // 9216
#define TDIM 12           // tiles per side
#define TSZ 8             // pixels per tile side
#define NTILE (TDIM*TDIM) // 144
#define MAXC 8            // max list chunks (NF/64)
#define BPT 8             // blocks per tile (8 px each)

#define SIGMA_F 1e-4f
#define GAMMA_F 1e-4f
#define BLUR_F  9.210240366975851e-4f   // log(1/1e-4 - 1) * 1e-4 -> f32
#define EPS_F   1e-10f
#define ZFAR_F  100.0f
#define ZNEAR_F 1.0f
#define RM      0.0304f                 // > sqrt(BLUR_F) = 0.0303484

#define SENT 0xFFFFFFFFFFFFFFFFull

__device__ __forceinline__ float frcp(float x) { return __builtin_amdgcn_rcpf(x); }

__device__ __forceinline__ float edge_d2(float px, float py,
                                         float ax, float ay,
                                         float bx, float by) {
    float abx = bx - ax, aby = by - ay;
    float apx = px - ax, apy = py - ay;
    float t = (apx*abx + apy*aby) * frcp(abx*abx + aby*aby + 1e-12f);
    t = fminf(fmaxf(t, 0.0f), 1.0f);
    float dx = apx - t*abx, dy = apy - t*aby;
    return dx*dx + dy*dy;
}

struct Rast { float b0, b1, b2, zpix, dists; };

__device__ __forceinline__ Rast rasterize_s(float px, float py,
                                            float v0x, float v0y, float v1x, float v1y,
                                            float v2x, float v2y,
                                            float z0, float z1, float z2) {
    Rast r;
    float e1x=v1x-v0x, e1y=v1y-v0y, e2x=v2x-v0x, e2y=v2y-v0y;
    float dx=px-v0x, dy=py-v0y;
    float rden = frcp(e1x*e2y - e1y*e2x + 1e-12f);
    r.b1 = (dx*e2y - dy*e2x) * rden;
    r.b2 = (e1x*dy - e1y*dx) * rden;
    r.b0 = 1.0f - r.b1 - r.b2;
    r.zpix = r.b0*z0 + r.b1*z1 + r.b2*z2;
    bool inside = (r.b0 >= 0.0f) && (r.b1 >= 0.0f) && (r.b2 >= 0.0f);
    float d2 = edge_d2(px, py, v0x, v0y, v1x, v1y);
    d2 = fminf(d2, edge_d2(px, py, v1x, v1y, v2x, v2y));
    d2 = fminf(d2, edge_d2(px, py, v2x, v2y, v0x, v0y));
    r.dists = inside ? -d2 : d2;
    return r;
}

__device__ __forceinline__ unsigned long long packzf(float z, int id) {
    return (((unsigned long long)__float_as_uint(z)) << 32) | (unsigned int)id;
}

__device__ __forceinline__ unsigned long long shflx64(unsigned long long v, int m) {
    int lo = __shfl_xor((int)(unsigned)(v & 0xffffffffull), m, 64);
    int hi = __shfl_xor((int)(unsigned)(v >> 32), m, 64);
    return ((unsigned long long)(unsigned)hi << 32) | (unsigned)lo;
}

// center-first concentric-ring tile ordering (heavy central tiles dispatch first)
__device__ __forceinline__ int ring_tile(int ord) {
    int r = ((int)__builtin_sqrtf((float)ord)) >> 1;
    while ((2*r+2)*(2*r+2) <= ord) ++r;
    while (r > 0 && (2*r)*(2*r) > ord) --r;
    int p = ord - 4*r*r;
    int side = 2*r + 2;
    int lo = TDIM/2 - 1 - r;       // 5 - r
    int hi = TDIM/2 + r;           // 6 + r
    int tx, ty;
    if (p < side)              { ty = lo; tx = lo + p; }
    else if (p < 2*side - 1)   { tx = hi; ty = lo + (p - side + 1); }
    else if (p < 3*side - 2)   { ty = hi; tx = hi - (p - (2*side - 1) + 1); }
    else                       { tx = lo; ty = hi - (p - (3*side - 2) + 1); }
    return ty * TDIM + tx;
}

// ============ single fused kernel: transform + bin + render, all in LDS ============
__global__ __launch_bounds__(512) void render_fused_kernel(
    const float* __restrict__ mpos,    // (B,M,3)
    const float* __restrict__ mrot,    // (B,M,3,3)
    const float* __restrict__ mscale,  // (B,M,3)
    const float* __restrict__ cpos,    // (B,3)
    const float* __restrict__ crot,    // (B,3,3)
    const float* __restrict__ verts,   // (M,V,3)
    const int*   __restrict__ faces,   // (M,Fm,3)
    const float* __restrict__ vcol,    // (M,V,3)
    float*       __restrict__ out)     // (B,H,W,4)
{
    const int blocksPerB = NTILE * BPT;
    const int b    = blockIdx.x / blocksPerB;
    const int rem  = blockIdx.x % blocksPerB;
    const int tile = ring_tile(rem / BPT);
    const int q    = rem % BPT;
    const int wv   = threadIdx.x >> 6;              // 0..7 (one pixel per wave)
    const int lane = threadIdx.x & 63;
    const int t    = threadIdx.x;

    __shared__ float2 svxy[NV];                            // 4 KB
    __shared__ float  svz[NV];                             // 2 KB
    __shared__ float4 scol[NV];                            // 8 KB
    __shared__ float  sbx0[NF], sby0[NF], sbx1[NF], sby1[NF]; // 8 KB
    __shared__ int    si0[NF], si1[NF], si2[NF];           // 6 KB
    __shared__ int    cl0[NF], cl1[NF], cl2[NF];           // 6 KB

    // camera for this batch
    float cr[9];
    #pragma unroll
    for (int i = 0; i < 9; ++i) cr[i] = crot[b*9 + i];
    const float cpx = cpos[b*3+0], cpy = cpos[b*3+1], cpz = cpos[b*3+2];

    // ---- phase 1: transform vertex t + colors -> LDS ----
    {
        int g = t;                         // 0..511
        int m = g >> 8;
        int sb = (b*MM + m)*3, rb = (b*MM + m)*9;
        float v0 = verts[g*3+0] * mscale[sb+0];
        float v1 = verts[g*3+1] * mscale[sb+1];
        float v2 = verts[g*3+2] * mscale[sb+2];
        float wx = mrot[rb+0]*v0 + mrot[rb+1]*v1 + mrot[rb+2]*v2 + mpos[sb+0];
        float wy = mrot[rb+3]*v0 + mrot[rb+4]*v1 + mrot[rb+5]*v2 + mpos[sb+1];
        float wz = mrot[rb+6]*v0 + mrot[rb+7]*v1 + mrot[rb+8]*v2 + mpos[sb+2];
        float cx = wx*cr[0] + wy*cr[3] + wz*cr[6] + cpx;
        float cy = wx*cr[1] + wy*cr[4] + wz*cr[7] + cpy;
        float cz = wx*cr[2] + wy*cr[5] + wz*cr[8] + cpz;
        float rz = frcp(cz);
        svxy[g] = make_float2(cx * rz, cy * rz);
        svz[g]  = cz;
        scol[g] = make_float4(vcol[g*3+0], vcol[g*3+1], vcol[g*3+2], 0.0f);
    }
    __syncthreads();

    // ---- phase 2: face gather + screen bbox -> LDS ----
    {
        int f = t;                         // 0..511
        int off = (f >> 8) << 8;
        int i0 = faces[f*3+0] + off;
        int i1 = faces[f*3+1] + off;
        int i2 = faces[f*3+2] + off;
        si0[f] = i0; si1[f] = i1; si2[f] = i2;
        float2 p0 = svxy[i0], p1 = svxy[i1], p2 = svxy[i2];
        sbx0[f] = fminf(fminf(p0.x,p1.x),p2.x);
        sby0[f] = fminf(fminf(p0.y,p1.y),p2.y);
        sbx1[f] = fmaxf(fmaxf(p0.x,p1.x),p2.x);
        sby1[f] = fmaxf(fmaxf(p0.y,p1.y),p2.y);
    }
    __syncthreads();

    // ---- phase 3: per-wave binning; preload bbox for ILP, then ballot rounds ----
    const int ty = tile / TDIM, tx = tile % TDIM;
    const float x_lo = -1.0f + tx * (2.0f / TDIM);
    const float x_hi = x_lo + 2.0f / TDIM;
    const float y_hi = 1.0f - ty * (2.0f / TDIM);
    const float y_lo = y_hi - 2.0f / TDIM;

    float bx0[8], by0[8], bx1[8], by1[8];
    #pragma unroll
    for (int k = 0; k < 8; ++k) {
        int f = (k << 6) | lane;
        bx0[k] = sbx0[f]; by0[k] = sby0[f];
        bx1[k] = sbx1[f]; by1[k] = sby1[f];
    }
    int hitm = 0;
    #pragma unroll
    for (int k = 0; k < 8; ++k) {
        bool hit = (bx0[k] - RM <= x_hi) && (bx1[k] + RM >= x_lo) &&
                   (by0[k] - RM <= y_hi) && (by1[k] + RM >= y_lo);
        hitm |= (hit ? 1 : 0) << k;
    }
    int L = 0;
    #pragma unroll
    for (int k = 0; k < 8; ++k) {
        bool hit = (hitm >> k) & 1;
        unsigned long long m = __ballot(hit);
        if (hit) {
            int f = (k << 6) | lane;
            int pos = L + __popcll(m & ((1ull << lane) - 1ull));
            cl0[pos] = si0[f];             // every wave writes identical values
            cl1[pos] = si1[f];
            cl2[pos] = si2[f];
        }
        L += __popcll(m);
    }
    // no sync: each wave wrote the complete compacted list itself

    // ---- pixel for this wave ----
    const int pi = ty * TSZ + q, pj = tx * TSZ + wv;
    const float px = ((float)pj + 0.5f) * (2.0f / WW) - 1.0f;
    const float py = 1.0f - ((float)pi + 0.5f) * (2.0f / HH);

    // ---- phase 4: scan compacted list; cache rast results per chunk (static idx) ----
    unsigned long long pk[MAXC];
    float rb0[MAXC], rb1[MAXC], rdist[MAXC];
    int validm = 0;
    #pragma unroll
    for (int c = 0; c < MAXC; ++c) {
        pk[c] = SENT;
        rb0[c] = 0.0f; rb1[c] = 0.0f; rdist[c] = 0.0f;
        if (c * 64 < L) {                            // wave-uniform
            int idx = c * 64 + lane;
            unsigned long long tt = SENT;
            if (idx < L) {
                int i0 = cl0[idx], i1 = cl1[idx], i2 = cl2[idx];
                float2 p0 = svxy[i0], p1 = svxy[i1], p2 = svxy[i2];
                float z0 = svz[i0], z1 = svz[i1], z2 = svz[i2];
                Rast r = rasterize_s(px, py, p0.x, p0.y, p1.x, p1.y,
                                     p2.x, p2.y, z0, z1, z2);
                if (r.zpix > 0.01f && r.dists <= BLUR_F) {
                    tt = packzf(r.zpix, idx);
                    rb0[c] = r.b0; rb1[c] = r.b1; rdist[c] = r.dists;
                }
            }
            pk[c] = tt;
            validm |= (tt != SENT ? 1 : 0) << c;
        }
    }

    const int c0 = __popc(validm);
    int cnt = c0;
    #pragma unroll
    for (int m = 1; m < 64; m <<= 1) cnt += __shfl_xor(cnt, m, 64);

    float nr = 0.0f, ng = 0.0f, nb = 0.0f, dn = 0.0f, ap = 1.0f;
    float zmaxv = EPS_F;

// full re-rasterize aggregation (sort / pop-min paths; id = list position)
#define AGG(pp, zz) do { \
        int p_ = (pp); float z_ = (zz); \
        int i0_ = cl0[p_], i1_ = cl1[p_], i2_ = cl2[p_]; \
        float2 q0_ = svxy[i0_], q1_ = svxy[i1_], q2_ = svxy[i2_]; \
        float z0_ = svz[i0_], z1_ = svz[i1_], z2_ = svz[i2_]; \
        Rast r_ = rasterize_s(px, py, q0_.x, q0_.y, q1_.x, q1_.y, \
                              q2_.x, q2_.y, z0_, z1_, z2_); \
        float prob_ = frcp(1.0f + __expf(r_.dists / SIGMA_F)); \
        float zinv_ = (ZFAR_F - z_) / (ZFAR_F - ZNEAR_F); \
        float w_ = prob_ * __expf((zinv_ - zmaxv) / GAMMA_F); \
        float4 c0_ = scol[i0_], c1_ = scol[i1_], c2_ = scol[i2_]; \
        nr += w_ * (r_.b0*c0_.x + r_.b1*c1_.x + r_.b2*c2_.x); \
        ng += w_ * (r_.b0*c0_.y + r_.b1*c1_.y + r_.b2*c2_.y); \
        nb += w_ * (r_.b0*c0_.z + r_.b1*c1_.z + r_.b2*c2_.z); \
        dn += w_; \
        ap *= (1.0f - prob_); \
    } while (0)

    if (cnt <= KK) {
        // ---- common path: all candidates included; cached rast results ----
        unsigned long long lmin = pk[0];
        #pragma unroll
        for (int c = 1; c < MAXC; ++c) lmin = (pk[c] < lmin) ? pk[c] : lmin;
        #pragma unroll
        for (int m = 1; m < 64; m <<= 1) {
            unsigned long long o2 = shflx64(lmin, m);
            lmin = (o2 < lmin) ? o2 : lmin;
        }
        if (cnt > 0) {
            float zming = __uint_as_float((unsigned)(lmin >> 32));
            zmaxv = fmaxf((ZFAR_F - zming) / (ZFAR_F - ZNEAR_F), EPS_F);
        }
        #pragma unroll
        for (int c = 0; c < MAXC; ++c)
            if (validm & (1 << c)) {
                int idx = c * 64 + lane;                 // this lane's candidate
                float z_ = __uint_as_float((unsigned)(pk[c] >> 32));
                float b0_ = rb0[c], b1_ = rb1[c];
                float b2_ = 1.0f - b0_ - b1_;
                float prob_ = frcp(1.0f + __expf(rdist[c] / SIGMA_F));
                float zinv_ = (ZFAR_F - z_) / (ZFAR_F - ZNEAR_F);
                float w_ = prob_ * __expf((zinv_ - zmaxv) / GAMMA_F);
                int i0_ = cl0[idx], i1_ = cl1[idx], i2_ = cl2[idx];
                float4 c0_ = scol[i0_], c1_ = scol[i1_], c2_ = scol[i2_];
                nr += w_ * (b0_*c0_.x + b1_*c1_.x + b2_*c2_.x);
                ng += w_ * (b0_*c0_.y + b1_*c1_.y + b2_*c2_.y);
                nb += w_ * (b0_*c0_.z + b1_*c1_.z + b2_*c2_.z);
                dn += w_;
                ap *= (1.0f - prob_);
            }
    } else if (L <= 64) {
        // ---- single-chunk sort path: bitonic ascending on registers ----
        unsigned long long v = pk[0];
        #pragma unroll
        for (int kk = 2; kk <= 64; kk <<= 1) {
            #pragma unroll
            for (int jj = kk >> 1; jj > 0; jj >>= 1) {
                unsigned long long o2 = shflx64(v, jj);
                bool kmin = ((lane & kk) == 0) == ((lane & jj) == 0);
                v = (kmin == (o2 < v)) ? o2 : v;
            }
        }
        unsigned z0b = (unsigned)__shfl((int)(unsigned)(v >> 32), 0, 64);
        zmaxv = fmaxf((ZFAR_F - __uint_as_float(z0b)) / (ZFAR_F - ZNEAR_F), EPS_F);
        if (lane < KK) {                             // cnt > 16 => all 16 valid
            int id = (int)(v & 0xffffffffull);
            float z = __uint_as_float((unsigned)(v >> 32));
            AGG(id, z);
        }
    } else {
        // ---- multi-chunk & cnt>16 -> pop-min 16 rounds ----
        int remm = validm, inclm = 0;
        float zming = 0.0f;
        for (int r = 0; r < KK; ++r) {
            unsigned long long lm = SENT;
            #pragma unroll
            for (int k = 0; k < MAXC; ++k)
                if (remm & (1 << k)) lm = (pk[k] < lm) ? pk[k] : lm;
            #pragma unroll
            for (int m = 1; m < 64; m <<= 1) {
                unsigned long long o2 = shflx64(lm, m);
                lm = (o2 < lm) ? o2 : lm;
            }
            if (r == 0) zming = __uint_as_float((unsigned)(lm >> 32));
            #pragma unroll
            for (int k = 0; k < MAXC; ++k)
                if ((remm & (1 << k)) && pk[k] == lm) { inclm |= 1 << k; remm &= ~(1 << k); }
        }
        zmaxv = fmaxf((ZFAR_F - zming) / (ZFAR_F - ZNEAR_F), EPS_F);
        #pragma unroll
        for (int k = 0; k < MAXC; ++k)
            if (inclm & (1 << k)) {
                int id = (int)(pk[k] & 0xffffffffull);
                float z = __uint_as_float((unsigned)(pk[k] >> 32));
                AGG(id, z);
            }
    }
#undef AGG

    // ---- wave butterfly reductions (deterministic fixed order) ----
    #pragma unroll
    for (int m = 1; m < 64; m <<= 1) {
        nr += __shfl_xor(nr, m, 64);
        ng += __shfl_xor(ng, m, 64);
        nb += __shfl_xor(nb, m, 64);
        dn += __shfl_xor(dn, m, 64);
        ap *= __shfl_xor(ap, m, 64);
    }
    if (lane == 0) {
        float delta = __expf((EPS_F - zmaxv) / GAMMA_F);
        float dd = dn + delta;
        float4 o4;
        o4.x = (nr + delta) / dd;
        o4.y = (ng + delta) / dd;
        o4.z = (nb + delta) / dd;
        o4.w = 1.0f - ap;
        *reinterpret_cast<float4*>(&out[((size_t)b * NPIX + pi * WW + pj) * 4]) = o4;
    }
}

extern "C" void kernel_launch(void* const* d_in, const int* in_sizes, int n_in,
                              void* d_out, int out_size, void* d_ws, size_t ws_size,
                              hipStream_t stream) {
    const float* mpos   = (const float*)d_in[0];
    const float* mrot   = (const float*)d_in[1];
    const float* mscale = (const float*)d_in[2];
    const float* cpos   = (const float*)d_in[3];
    const float* crot   = (const float*)d_in[4];
    const float* verts  = (const float*)d_in[5];
    const int*   faces  = (const int*)d_in[6];
    const float* vcol   = (const float*)d_in[7];
    float*       out    = (float*)d_out;

    const int B = in_sizes[3] / 3;                  // cam_pos is (B,3)
    dim3 grid(B * NTILE * BPT), block(512);
    render_fused_kernel<<<grid, block, 0, stream>>>(
        mpos, mrot, mscale, cpos, crot, verts, faces, vcol, out);
}

// Round 14
// 42.067 us; speedup vs baseline: 1.1911x; 1.1911x over previous
//
#include <hip/hip_runtime.h>

#pragma clang fp contract(off)

#define HH 96
#define WW 96
#define KK 16
#define MM 2
#define NF 512            // M * Fm
#define NV 512            // M * V
#define NPIX (HH*WW)      // 9216
#define TDIM 12           // tiles per side
#define TSZ 8             // pixels per tile side
#define NTILE (TDIM*TDIM) // 144
#define MAXC 8            // max list chunks (NF/64)
#define BPT 8             // blocks per tile (8 px each)

#define SIGMA_F 1e-4f
#define GAMMA_F 1e-4f
#define BLUR_F  9.210240366975851e-4f   // log(1/1e-4 - 1) * 1e-4 -> f32
#define EPS_F   1e-10f
#define ZFAR_F  100.0f
#define ZNEAR_F 1.0f
#define RM      0.0304f                 // > sqrt(BLUR_F) = 0.0303484

#define SENT 0xFFFFFFFFFFFFFFFFull

__device__ __forceinline__ float frcp(float x) { return __builtin_amdgcn_rcpf(x); }

__device__ __forceinline__ float edge_d2(float px, float py,
                                         float ax, float ay,
                                         float bx, float by) {
    float abx = bx - ax, aby = by - ay;
    float apx = px - ax, apy = py - ay;
    float t = (apx*abx + apy*aby) * frcp(abx*abx + aby*aby + 1e-12f);
    t = fminf(fmaxf(t, 0.0f), 1.0f);
    float dx = apx - t*abx, dy = apy - t*aby;
    return dx*dx + dy*dy;
}

struct Rast { float b0, b1, b2, zpix, dists; };

__device__ __forceinline__ Rast rasterize_s(float px, float py,
                                            float v0x, float v0y, float v1x, float v1y,
                                            float v2x, float v2y,
                                            float z0, float z1, float z2) {
    Rast r;
    float e1x=v1x-v0x, e1y=v1y-v0y, e2x=v2x-v0x, e2y=v2y-v0y;
    float dx=px-v0x, dy=py-v0y;
    float rden = frcp(e1x*e2y - e1y*e2x + 1e-12f);
    r.b1 = (dx*e2y - dy*e2x) * rden;
    r.b2 = (e1x*dy - e1y*dx) * rden;
    r.b0 = 1.0f - r.b1 - r.b2;
    r.zpix = r.b0*z0 + r.b1*z1 + r.b2*z2;
    bool inside = (r.b0 >= 0.0f) && (r.b1 >= 0.0f) && (r.b2 >= 0.0f);
    float d2 = edge_d2(px, py, v0x, v0y, v1x, v1y);
    d2 = fminf(d2, edge_d2(px, py, v1x, v1y, v2x, v2y));
    d2 = fminf(d2, edge_d2(px, py, v2x, v2y, v0x, v0y));
    r.dists = inside ? -d2 : d2;
    return r;
}

__device__ __forceinline__ unsigned long long packzf(float z, int id) {
    return (((unsigned long long)__float_as_uint(z)) << 32) | (unsigned int)id;
}

__device__ __forceinline__ unsigned long long shflx64(unsigned long long v, int m) {
    int lo = __shfl_xor((int)(unsigned)(v & 0xffffffffull), m, 64);
    int hi = __shfl_xor((int)(unsigned)(v >> 32), m, 64);
    return ((unsigned long long)(unsigned)hi << 32) | (unsigned)lo;
}

// center-first concentric-ring tile ordering (heavy central tiles dispatch first)
__device__ __forceinline__ int ring_tile(int ord) {
    int r = ((int)__builtin_sqrtf((float)ord)) >> 1;
    while ((2*r+2)*(2*r+2) <= ord) ++r;
    while (r > 0 && (2*r)*(2*r) > ord) --r;
    int p = ord - 4*r*r;
    int side = 2*r + 2;
    int lo = TDIM/2 - 1 - r;       // 5 - r
    int hi = TDIM/2 + r;           // 6 + r
    int tx, ty;
    if (p < side)              { ty = lo; tx = lo + p; }
    else if (p < 2*side - 1)   { tx = hi; ty = lo + (p - side + 1); }
    else if (p < 3*side - 2)   { ty = hi; tx = hi - (p - (2*side - 1) + 1); }
    else                       { tx = lo; ty = hi - (p - (3*side - 2) + 1); }
    return ty * TDIM + tx;
}

// ============ single fused kernel: transform + bin + render, all in LDS ============
__global__ __launch_bounds__(512) void render_fused_kernel(
    const float* __restrict__ mpos,    // (B,M,3)
    const float* __restrict__ mrot,    // (B,M,3,3)
    const float* __restrict__ mscale,  // (B,M,3)
    const float* __restrict__ cpos,    // (B,3)
    const float* __restrict__ crot,    // (B,3,3)
    const float* __restrict__ verts,   // (M,V,3)
    const int*   __restrict__ faces,   // (M,Fm,3)
    const float* __restrict__ vcol,    // (M,V,3)
    float*       __restrict__ out)     // (B,H,W,4)
{
    const int blocksPerB = NTILE * BPT;
    const int b    = blockIdx.x / blocksPerB;
    const int rem  = blockIdx.x % blocksPerB;
    const int tile = ring_tile(rem / BPT);
    const int q    = rem % BPT;
    const int wv   = threadIdx.x >> 6;              // 0..7 (one pixel per wave)
    const int lane = threadIdx.x & 63;
    const int t    = threadIdx.x;

    __shared__ float2 svxy[NV];                            // 4 KB
    __shared__ float  svz[NV];                             // 2 KB
    __shared__ float4 scol[NV];                            // 8 KB
    __shared__ float  sbx0[NF], sby0[NF], sbx1[NF], sby1[NF]; // 8 KB
    __shared__ int    si0[NF], si1[NF], si2[NF];           // 6 KB
    __shared__ int    cl0[NF], cl1[NF], cl2[NF];           // 6 KB

    // camera for this batch
    float cr[9];
    #pragma unroll
    for (int i = 0; i < 9; ++i) cr[i] = crot[b*9 + i];
    const float cpx = cpos[b*3+0], cpy = cpos[b*3+1], cpz = cpos[b*3+2];

    // ---- phase 1: transform vertex t + colors -> LDS ----
    {
        int g = t;                         // 0..511
        int m = g >> 8;
        int sb = (b*MM + m)*3, rb = (b*MM + m)*9;
        float v0 = verts[g*3+0] * mscale[sb+0];
        float v1 = verts[g*3+1] * mscale[sb+1];
        float v2 = verts[g*3+2] * mscale[sb+2];
        float wx = mrot[rb+0]*v0 + mrot[rb+1]*v1 + mrot[rb+2]*v2 + mpos[sb+0];
        float wy = mrot[rb+3]*v0 + mrot[rb+4]*v1 + mrot[rb+5]*v2 + mpos[sb+1];
        float wz = mrot[rb+6]*v0 + mrot[rb+7]*v1 + mrot[rb+8]*v2 + mpos[sb+2];
        float cx = wx*cr[0] + wy*cr[3] + wz*cr[6] + cpx;
        float cy = wx*cr[1] + wy*cr[4] + wz*cr[7] + cpy;
        float cz = wx*cr[2] + wy*cr[5] + wz*cr[8] + cpz;
        svxy[g] = make_float2(cx / cz, cy / cz);
        svz[g]  = cz;
        scol[g] = make_float4(vcol[g*3+0], vcol[g*3+1], vcol[g*3+2], 0.0f);
    }
    __syncthreads();

    // ---- phase 2: face gather + screen bbox -> LDS ----
    {
        int f = t;                         // 0..511
        int off = (f >> 8) << 8;
        int i0 = faces[f*3+0] + off;
        int i1 = faces[f*3+1] + off;
        int i2 = faces[f*3+2] + off;
        si0[f] = i0; si1[f] = i1; si2[f] = i2;
        float2 p0 = svxy[i0], p1 = svxy[i1], p2 = svxy[i2];
        sbx0[f] = fminf(fminf(p0.x,p1.x),p2.x);
        sby0[f] = fminf(fminf(p0.y,p1.y),p2.y);
        sbx1[f] = fmaxf(fmaxf(p0.x,p1.x),p2.x);
        sby1[f] = fmaxf(fmaxf(p0.y,p1.y),p2.y);
    }
    __syncthreads();

    // ---- phase 3: per-wave binning; preload bbox for ILP, then ballot rounds ----
    const int ty = tile / TDIM, tx = tile % TDIM;
    const float x_lo = -1.0f + tx * (2.0f / TDIM);
    const float x_hi = x_lo + 2.0f / TDIM;
    const float y_hi = 1.0f - ty * (2.0f / TDIM);
    const float y_lo = y_hi - 2.0f / TDIM;

    float bx0[8], by0[8], bx1[8], by1[8];
    #pragma unroll
    for (int k = 0; k < 8; ++k) {
        int f = (k << 6) | lane;
        bx0[k] = sbx0[f]; by0[k] = sby0[f];
        bx1[k] = sbx1[f]; by1[k] = sby1[f];
    }
    int hitm = 0;
    #pragma unroll
    for (int k = 0; k < 8; ++k) {
        bool hit = (bx0[k] - RM <= x_hi) && (bx1[k] + RM >= x_lo) &&
                   (by0[k] - RM <= y_hi) && (by1[k] + RM >= y_lo);
        hitm |= (hit ? 1 : 0) << k;
    }
    int L = 0;
    #pragma unroll
    for (int k = 0; k < 8; ++k) {
        bool hit = (hitm >> k) & 1;
        unsigned long long m = __ballot(hit);
        if (hit) {
            int f = (k << 6) | lane;
            int pos = L + __popcll(m & ((1ull << lane) - 1ull));
            cl0[pos] = si0[f];             // every wave writes identical values
            cl1[pos] = si1[f];
            cl2[pos] = si2[f];
        }
        L += __popcll(m);
    }
    // no sync: each wave wrote the complete compacted list itself

    // ---- pixel for this wave ----
    const int pi = ty * TSZ + q, pj = tx * TSZ + wv;
    const float px = ((float)pj + 0.5f) * (2.0f / WW) - 1.0f;
    const float py = 1.0f - ((float)pi + 0.5f) * (2.0f / HH);

    // ---- phase 4: scan + ONLINE aggregation (valid iff cnt<=KK at the end) ----
    unsigned long long pk[MAXC];
    int validm = 0;
    float nr = 0.0f, ng = 0.0f, nb = 0.0f, dn = 0.0f, ap = 1.0f;
    float zm = EPS_F;                                 // running max of zinv

    #pragma unroll
    for (int c = 0; c < MAXC; ++c) {
        pk[c] = SENT;
        if (c * 64 < L) {                            // wave-uniform
            int idx = c * 64 + lane;
            unsigned long long tt = SENT;
            if (idx < L) {
                int i0 = cl0[idx], i1 = cl1[idx], i2 = cl2[idx];
                float2 p0 = svxy[i0], p1 = svxy[i1], p2 = svxy[i2];
                float z0 = svz[i0], z1 = svz[i1], z2 = svz[i2];
                Rast r = rasterize_s(px, py, p0.x, p0.y, p1.x, p1.y,
                                     p2.x, p2.y, z0, z1, z2);
                if (r.zpix > 0.01f && r.dists <= BLUR_F) {
                    tt = packzf(r.zpix, idx);
                    // online accumulate (relative to running max zm)
                    float zinv = (ZFAR_F - r.zpix) / (ZFAR_F - ZNEAR_F);
                    if (zinv > zm) {
                        float s = __expf(zm - zinv);  // note: GAMMA==1e-4 divides below
                        s = __expf((zm - zinv) / GAMMA_F);
                        nr *= s; ng *= s; nb *= s; dn *= s;
                        zm = zinv;
                    }
                    float prob = frcp(1.0f + __expf(r.dists / SIGMA_F));
                    float w = prob * __expf((zinv - zm) / GAMMA_F);
                    float4 c0_ = scol[i0], c1_ = scol[i1], c2_ = scol[i2];
                    nr += w * (r.b0*c0_.x + r.b1*c1_.x + r.b2*c2_.x);
                    ng += w * (r.b0*c0_.y + r.b1*c1_.y + r.b2*c2_.y);
                    nb += w * (r.b0*c0_.z + r.b1*c1_.z + r.b2*c2_.z);
                    dn += w;
                    ap *= (1.0f - prob);
                }
            }
            pk[c] = tt;
            validm |= (tt != SENT ? 1 : 0) << c;
        }
    }

    const int c0 = __popc(validm);
    int cnt = c0;
    #pragma unroll
    for (int m = 1; m < 64; m <<= 1) cnt += __shfl_xor(cnt, m, 64);

    float zmaxv = zm;

// full re-rasterize aggregation (sort / pop-min paths; id = list position)
#define AGG(pp, zz) do { \
        int p_ = (pp); float z_ = (zz); \
        int i0_ = cl0[p_], i1_ = cl1[p_], i2_ = cl2[p_]; \
        float2 q0_ = svxy[i0_], q1_ = svxy[i1_], q2_ = svxy[i2_]; \
        float z0_ = svz[i0_], z1_ = svz[i1_], z2_ = svz[i2_]; \
        Rast r_ = rasterize_s(px, py, q0_.x, q0_.y, q1_.x, q1_.y, \
                              q2_.x, q2_.y, z0_, z1_, z2_); \
        float prob_ = frcp(1.0f + __expf(r_.dists / SIGMA_F)); \
        float zinv_ = (ZFAR_F - z_) / (ZFAR_F - ZNEAR_F); \
        float w_ = prob_ * __expf((zinv_ - zmaxv) / GAMMA_F); \
        float4 c0_ = scol[i0_], c1_ = scol[i1_], c2_ = scol[i2_]; \
        nr += w_ * (r_.b0*c0_.x + r_.b1*c1_.x + r_.b2*c2_.x); \
        ng += w_ * (r_.b0*c0_.y + r_.b1*c1_.y + r_.b2*c2_.y); \
        nb += w_ * (r_.b0*c0_.z + r_.b1*c1_.z + r_.b2*c2_.z); \
        dn += w_; \
        ap *= (1.0f - prob_); \
    } while (0)

    if (cnt <= KK) {
        // online accumulation is exact for this case — nothing more to do
    } else if (L <= 64) {
        // ---- single-chunk sort path: bitonic ascending on registers ----
        nr = 0.0f; ng = 0.0f; nb = 0.0f; dn = 0.0f; ap = 1.0f;
        unsigned long long v = pk[0];
        #pragma unroll
        for (int kk = 2; kk <= 64; kk <<= 1) {
            #pragma unroll
            for (int jj = kk >> 1; jj > 0; jj >>= 1) {
                unsigned long long o2 = shflx64(v, jj);
                bool kmin = ((lane & kk) == 0) == ((lane & jj) == 0);
                v = (kmin == (o2 < v)) ? o2 : v;
            }
        }
        unsigned z0b = (unsigned)__shfl((int)(unsigned)(v >> 32), 0, 64);
        zmaxv = fmaxf((ZFAR_F - __uint_as_float(z0b)) / (ZFAR_F - ZNEAR_F), EPS_F);
        if (lane < KK) {                             // cnt > 16 => all 16 valid
            int id = (int)(v & 0xffffffffull);
            float z = __uint_as_float((unsigned)(v >> 32));
            AGG(id, z);
        }
    } else {
        // ---- multi-chunk & cnt>16 -> pop-min 16 rounds ----
        nr = 0.0f; ng = 0.0f; nb = 0.0f; dn = 0.0f; ap = 1.0f;
        int remm = validm, inclm = 0;
        float zming = 0.0f;
        for (int r = 0; r < KK; ++r) {
            unsigned long long lm = SENT;
            #pragma unroll
            for (int k = 0; k < MAXC; ++k)
                if (remm & (1 << k)) lm = (pk[k] < lm) ? pk[k] : lm;
            #pragma unroll
            for (int m = 1; m < 64; m <<= 1) {
                unsigned long long o2 = shflx64(lm, m);
                lm = (o2 < lm) ? o2 : lm;
            }
            if (r == 0) zming = __uint_as_float((unsigned)(lm >> 32));
            #pragma unroll
            for (int k = 0; k < MAXC; ++k)
                if ((remm & (1 << k)) && pk[k] == lm) { inclm |= 1 << k; remm &= ~(1 << k); }
        }
        zmaxv = fmaxf((ZFAR_F - zming) / (ZFAR_F - ZNEAR_F), EPS_F);
        #pragma unroll
        for (int k = 0; k < MAXC; ++k)
            if (inclm & (1 << k)) {
                int id = (int)(pk[k] & 0xffffffffull);
                float z = __uint_as_float((unsigned)(pk[k] >> 32));
                AGG(id, z);
            }
    }
#undef AGG

    // ---- wave butterfly reductions (deterministic fixed order) ----
    // fold zmaxv across lanes first (online path: per-lane running max)
    #pragma unroll
    for (int m = 1; m < 64; m <<= 1) zmaxv = fmaxf(zmaxv, __shfl_xor(zmaxv, m, 64));
    // rescale each lane's accumulators to the wave max before summing (online path);
    // for fallback paths zmaxv is already wave-uniform so s==1 exactly.
    {
        float s = __expf((zm - zmaxv) / GAMMA_F);
        if (cnt <= KK) { nr *= s; ng *= s; nb *= s; dn *= s; }
    }
    #pragma unroll
    for (int m = 1; m < 64; m <<= 1) {
        nr += __shfl_xor(nr, m, 64);
        ng += __shfl_xor(ng, m, 64);
        nb += __shfl_xor(nb, m, 64);
        dn += __shfl_xor(dn, m, 64);
        ap *= __shfl_xor(ap, m, 64);
    }
    if (lane == 0) {
        float delta = __expf((EPS_F - zmaxv) / GAMMA_F);
        float dd = dn + delta;
        float4 o4;
        o4.x = (nr + delta) / dd;
        o4.y = (ng + delta) / dd;
        o4.z = (nb + delta) / dd;
        o4.w = 1.0f - ap;
        *reinterpret_cast<float4*>(&out[((size_t)b * NPIX + pi * WW + pj) * 4]) = o4;
    }
}

extern "C" void kernel_launch(void* const* d_in, const int* in_sizes, int n_in,
                              void* d_out, int out_size, void* d_ws, size_t ws_size,
                              hipStream_t stream) {
    const float* mpos   = (const float*)d_in[0];
    const float* mrot   = (const float*)d_in[1];
    const float* mscale = (const float*)d_in[2];
    const float* cpos   = (const float*)d_in[3];
    const float* crot   = (const float*)d_in[4];
    const float* verts  = (const float*)d_in[5];
    const int*   faces  = (const int*)d_in[6];
    const float* vcol   = (const float*)d_in[7];
    float*       out    = (float*)d_out;

    const int B = in_sizes[3] / 3;                  // cam_pos is (B,3)
    dim3 grid(B * NTILE * BPT), block(512);
    render_fused_kernel<<<grid, block, 0, stream>>>(
        mpos, mrot, mscale, cpos, crot, verts, faces, vcol, out);
}

// Round 15
// 39.278 us; speedup vs baseline: 1.2757x; 1.0710x over previous
//
#include <hip/hip_runtime.h>

#pragma clang fp contract(off)

#define HH 96
#define WW 96
#define KK 16
#define MM 2
#define NF 512            // M * Fm
#define NV 512            // M * V
#define NPIX (HH*WW)      // 9216
#define TDIM 12           // tiles per side
#define TSZ 8             // pixels per tile side
#define NTILE (TDIM*TDIM) // 144
#define MAXC 8            // max list chunks (NF/64)
#define BPT 8             // blocks per tile (8 px each)

#define SIGMA_F 1e-4f
#define GAMMA_F 1e-4f
#define BLUR_F  9.210240366975851e-4f   // log(1/1e-4 - 1) * 1e-4 -> f32
#define EPS_F   1e-10f
#define ZFAR_F  100.0f
#define ZNEAR_F 1.0f
#define RM      0.0304f                 // > sqrt(BLUR_F) = 0.0303484

#define SENT 0xFFFFFFFFFFFFFFFFull

__device__ __forceinline__ float frcp(float x) { return __builtin_amdgcn_rcpf(x); }

__device__ __forceinline__ float edge_d2(float px, float py,
                                         float ax, float ay,
                                         float bx, float by) {
    float abx = bx - ax, aby = by - ay;
    float apx = px - ax, apy = py - ay;
    float t = (apx*abx + apy*aby) * frcp(abx*abx + aby*aby + 1e-12f);
    t = fminf(fmaxf(t, 0.0f), 1.0f);
    float dx = apx - t*abx, dy = apy - t*aby;
    return dx*dx + dy*dy;
}

struct Rast { float b0, b1, b2, zpix, dists; };

__device__ __forceinline__ Rast rasterize_s(float px, float py,
                                            float v0x, float v0y, float v1x, float v1y,
                                            float v2x, float v2y,
                                            float z0, float z1, float z2) {
    Rast r;
    float e1x=v1x-v0x, e1y=v1y-v0y, e2x=v2x-v0x, e2y=v2y-v0y;
    float dx=px-v0x, dy=py-v0y;
    float rden = frcp(e1x*e2y - e1y*e2x + 1e-12f);
    r.b1 = (dx*e2y - dy*e2x) * rden;
    r.b2 = (e1x*dy - e1y*dx) * rden;
    r.b0 = 1.0f - r.b1 - r.b2;
    r.zpix = r.b0*z0 + r.b1*z1 + r.b2*z2;
    bool inside = (r.b0 >= 0.0f) && (r.b1 >= 0.0f) && (r.b2 >= 0.0f);
    float d2 = edge_d2(px, py, v0x, v0y, v1x, v1y);
    d2 = fminf(d2, edge_d2(px, py, v1x, v1y, v2x, v2y));
    d2 = fminf(d2, edge_d2(px, py, v2x, v2y, v0x, v0y));
    r.dists = inside ? -d2 : d2;
    return r;
}

__device__ __forceinline__ unsigned long long packzf(float z, int id) {
    return (((unsigned long long)__float_as_uint(z)) << 32) | (unsigned int)id;
}

__device__ __forceinline__ unsigned long long shflx64(unsigned long long v, int m) {
    int lo = __shfl_xor((int)(unsigned)(v & 0xffffffffull), m, 64);
    int hi = __shfl_xor((int)(unsigned)(v >> 32), m, 64);
    return ((unsigned long long)(unsigned)hi << 32) | (unsigned)lo;
}

// center-first concentric-ring tile ordering (heavy central tiles dispatch first)
__device__ __forceinline__ int ring_tile(int ord) {
    int r = ((int)__builtin_sqrtf((float)ord)) >> 1;
    while ((2*r+2)*(2*r+2) <= ord) ++r;
    while (r > 0 && (2*r)*(2*r) > ord) --r;
    int p = ord - 4*r*r;
    int side = 2*r + 2;
    int lo = TDIM/2 - 1 - r;       // 5 - r
    int hi = TDIM/2 + r;           // 6 + r
    int tx, ty;
    if (p < side)              { ty = lo; tx = lo + p; }
    else if (p < 2*side - 1)   { tx = hi; ty = lo + (p - side + 1); }
    else if (p < 3*side - 2)   { ty = hi; tx = hi - (p - (2*side - 1) + 1); }
    else                       { tx = lo; ty = hi - (p - (3*side - 2) + 1); }
    return ty * TDIM + tx;
}

// ============ single fused kernel: transform + bin + render, all in LDS ============
__global__ __launch_bounds__(512) void render_fused_kernel(
    const float* __restrict__ mpos,    // (B,M,3)
    const float* __restrict__ mrot,    // (B,M,3,3)
    const float* __restrict__ mscale,  // (B,M,3)
    const float* __restrict__ cpos,    // (B,3)
    const float* __restrict__ crot,    // (B,3,3)
    const float* __restrict__ verts,   // (M,V,3)
    const int*   __restrict__ faces,   // (M,Fm,3)
    const float* __restrict__ vcol,    // (M,V,3)
    float*       __restrict__ out)     // (B,H,W,4)
{
    const int blocksPerB = NTILE * BPT;
    const int b    = blockIdx.x / blocksPerB;
    const int rem  = blockIdx.x % blocksPerB;
    const int tile = ring_tile(rem / BPT);
    const int q    = rem % BPT;
    const int wv   = threadIdx.x >> 6;              // 0..7 (one pixel per wave)
    const int lane = threadIdx.x & 63;
    const int t    = threadIdx.x;

    __shared__ float2 svxy[NV];                            // 4 KB
    __shared__ float  svz[NV];                             // 2 KB
    __shared__ float4 scol[NV];                            // 8 KB
    __shared__ float  sbx0[NF], sby0[NF], sbx1[NF], sby1[NF]; // 8 KB
    __shared__ int    si0[NF], si1[NF], si2[NF];           // 6 KB
    __shared__ int    cl0[NF], cl1[NF], cl2[NF];           // 6 KB

    // camera for this batch
    float cr[9];
    #pragma unroll
    for (int i = 0; i < 9; ++i) cr[i] = crot[b*9 + i];
    const float cpx = cpos[b*3+0], cpy = cpos[b*3+1], cpz = cpos[b*3+2];

    // ---- phase 1: transform vertex t + colors -> LDS ----
    {
        int g = t;                         // 0..511
        int m = g >> 8;
        int sb = (b*MM + m)*3, rb = (b*MM + m)*9;
        float v0 = verts[g*3+0] * mscale[sb+0];
        float v1 = verts[g*3+1] * mscale[sb+1];
        float v2 = verts[g*3+2] * mscale[sb+2];
        float wx = mrot[rb+0]*v0 + mrot[rb+1]*v1 + mrot[rb+2]*v2 + mpos[sb+0];
        float wy = mrot[rb+3]*v0 + mrot[rb+4]*v1 + mrot[rb+5]*v2 + mpos[sb+1];
        float wz = mrot[rb+6]*v0 + mrot[rb+7]*v1 + mrot[rb+8]*v2 + mpos[sb+2];
        float cx = wx*cr[0] + wy*cr[3] + wz*cr[6] + cpx;
        float cy = wx*cr[1] + wy*cr[4] + wz*cr[7] + cpy;
        float cz = wx*cr[2] + wy*cr[5] + wz*cr[8] + cpz;
        svxy[g] = make_float2(cx / cz, cy / cz);
        svz[g]  = cz;
        scol[g] = make_float4(vcol[g*3+0], vcol[g*3+1], vcol[g*3+2], 0.0f);
    }
    __syncthreads();

    // ---- phase 2: face gather + screen bbox -> LDS ----
    {
        int f = t;                         // 0..511
        int off = (f >> 8) << 8;
        int i0 = faces[f*3+0] + off;
        int i1 = faces[f*3+1] + off;
        int i2 = faces[f*3+2] + off;
        si0[f] = i0; si1[f] = i1; si2[f] = i2;
        float2 p0 = svxy[i0], p1 = svxy[i1], p2 = svxy[i2];
        sbx0[f] = fminf(fminf(p0.x,p1.x),p2.x);
        sby0[f] = fminf(fminf(p0.y,p1.y),p2.y);
        sbx1[f] = fmaxf(fmaxf(p0.x,p1.x),p2.x);
        sby1[f] = fmaxf(fmaxf(p0.y,p1.y),p2.y);
    }
    __syncthreads();

    // ---- phase 3: per-wave binning; preload bbox for ILP, then ballot rounds ----
    const int ty = tile / TDIM, tx = tile % TDIM;
    const float x_lo = -1.0f + tx * (2.0f / TDIM);
    const float x_hi = x_lo + 2.0f / TDIM;
    const float y_hi = 1.0f - ty * (2.0f / TDIM);
    const float y_lo = y_hi - 2.0f / TDIM;

    float bx0[8], by0[8], bx1[8], by1[8];
    #pragma unroll
    for (int k = 0; k < 8; ++k) {
        int f = (k << 6) | lane;
        bx0[k] = sbx0[f]; by0[k] = sby0[f];
        bx1[k] = sbx1[f]; by1[k] = sby1[f];
    }
    int hitm = 0;
    #pragma unroll
    for (int k = 0; k < 8; ++k) {
        bool hit = (bx0[k] - RM <= x_hi) && (bx1[k] + RM >= x_lo) &&
                   (by0[k] - RM <= y_hi) && (by1[k] + RM >= y_lo);
        hitm |= (hit ? 1 : 0) << k;
    }
    int L = 0;
    #pragma unroll
    for (int k = 0; k < 8; ++k) {
        bool hit = (hitm >> k) & 1;
        unsigned long long m = __ballot(hit);
        if (hit) {
            int f = (k << 6) | lane;
            int pos = L + __popcll(m & ((1ull << lane) - 1ull));
            cl0[pos] = si0[f];             // every wave writes identical values
            cl1[pos] = si1[f];
            cl2[pos] = si2[f];
        }
        L += __popcll(m);
    }
    // no sync: each wave wrote the complete compacted list itself

    // ---- pixel for this wave ----
    const int pi = ty * TSZ + q, pj = tx * TSZ + wv;
    const float px = ((float)pj + 0.5f) * (2.0f / WW) - 1.0f;
    const float py = 1.0f - ((float)pi + 0.5f) * (2.0f / HH);

    // ---- phase 4: scan compacted list (stride-1 cl reads -> sv gathers) ----
    unsigned long long pk[MAXC];
    int validm = 0;
    #pragma unroll
    for (int c = 0; c < MAXC; ++c) {
        pk[c] = SENT;
        if (c * 64 < L) {                            // wave-uniform
            int idx = c * 64 + lane;
            unsigned long long tt = SENT;
            if (idx < L) {
                int i0 = cl0[idx], i1 = cl1[idx], i2 = cl2[idx];
                float2 p0 = svxy[i0], p1 = svxy[i1], p2 = svxy[i2];
                float z0 = svz[i0], z1 = svz[i1], z2 = svz[i2];
                Rast r = rasterize_s(px, py, p0.x, p0.y, p1.x, p1.y,
                                     p2.x, p2.y, z0, z1, z2);
                if (r.zpix > 0.01f && r.dists <= BLUR_F) tt = packzf(r.zpix, idx);
            }
            pk[c] = tt;
            validm |= (tt != SENT ? 1 : 0) << c;
        }
    }

    const int c0 = __popc(validm);
    int cnt = c0;
    #pragma unroll
    for (int m = 1; m < 64; m <<= 1) cnt += __shfl_xor(cnt, m, 64);

    float nr = 0.0f, ng = 0.0f, nb = 0.0f, dn = 0.0f, ap = 1.0f;
    float zmaxv = EPS_F;

#define AGG(pp, zz) do { \
        int p_ = (pp); float z_ = (zz); \
        int i0_ = cl0[p_], i1_ = cl1[p_], i2_ = cl2[p_]; \
        float2 q0_ = svxy[i0_], q1_ = svxy[i1_], q2_ = svxy[i2_]; \
        float z0_ = svz[i0_], z1_ = svz[i1_], z2_ = svz[i2_]; \
        Rast r_ = rasterize_s(px, py, q0_.x, q0_.y, q1_.x, q1_.y, \
                              q2_.x, q2_.y, z0_, z1_, z2_); \
        float prob_ = frcp(1.0f + __expf(r_.dists / SIGMA_F)); \
        float zinv_ = (ZFAR_F - z_) / (ZFAR_F - ZNEAR_F); \
        float w_ = prob_ * __expf((zinv_ - zmaxv) / GAMMA_F); \
        float4 c0_ = scol[i0_], c1_ = scol[i1_], c2_ = scol[i2_]; \
        nr += w_ * (r_.b0*c0_.x + r_.b1*c1_.x + r_.b2*c2_.x); \
        ng += w_ * (r_.b0*c0_.y + r_.b1*c1_.y + r_.b2*c2_.y); \
        nb += w_ * (r_.b0*c0_.z + r_.b1*c1_.z + r_.b2*c2_.z); \
        dn += w_; \
        ap *= (1.0f - prob_); \
    } while (0)

    if (cnt <= KK) {
        // ---- common path: all candidates included; zmax from butterfly min ----
        unsigned long long lmin = pk[0];
        #pragma unroll
        for (int c = 1; c < MAXC; ++c) lmin = (pk[c] < lmin) ? pk[c] : lmin;
        #pragma unroll
        for (int m = 1; m < 64; m <<= 1) {
            unsigned long long o2 = shflx64(lmin, m);
            lmin = (o2 < lmin) ? o2 : lmin;
        }
        if (cnt > 0) {
            float zming = __uint_as_float((unsigned)(lmin >> 32));
            zmaxv = fmaxf((ZFAR_F - zming) / (ZFAR_F - ZNEAR_F), EPS_F);
        }
        #pragma unroll
        for (int c = 0; c < MAXC; ++c)
            if (validm & (1 << c)) {
                int id = (int)(pk[c] & 0xffffffffull);
                float z = __uint_as_float((unsigned)(pk[c] >> 32));
                AGG(id, z);
            }
    } else if (L <= 64) {
        // ---- single-chunk sort path: bitonic ascending on registers ----
        unsigned long long v = pk[0];
        #pragma unroll
        for (int kk = 2; kk <= 64; kk <<= 1) {
            #pragma unroll
            for (int jj = kk >> 1; jj > 0; jj >>= 1) {
                unsigned long long o2 = shflx64(v, jj);
                bool kmin = ((lane & kk) == 0) == ((lane & jj) == 0);
                v = (kmin == (o2 < v)) ? o2 : v;
            }
        }
        unsigned z0b = (unsigned)__shfl((int)(unsigned)(v >> 32), 0, 64);
        zmaxv = fmaxf((ZFAR_F - __uint_as_float(z0b)) / (ZFAR_F - ZNEAR_F), EPS_F);
        if (lane < KK) {                             // cnt > 16 => all 16 valid
            int id = (int)(v & 0xffffffffull);
            float z = __uint_as_float((unsigned)(v >> 32));
            AGG(id, z);
        }
    } else {
        // ---- multi-chunk & cnt>16 -> pop-min 16 rounds ----
        int remm = validm, inclm = 0;
        float zming = 0.0f;
        for (int r = 0; r < KK; ++r) {
            unsigned long long lm = SENT;
            #pragma unroll
            for (int k = 0; k < MAXC; ++k)
                if (remm & (1 << k)) lm = (pk[k] < lm) ? pk[k] : lm;
            #pragma unroll
            for (int m = 1; m < 64; m <<= 1) {
                unsigned long long o2 = shflx64(lm, m);
                lm = (o2 < lm) ? o2 : lm;
            }
            if (r == 0) zming = __uint_as_float((unsigned)(lm >> 32));
            #pragma unroll
            for (int k = 0; k < MAXC; ++k)
                if ((remm & (1 << k)) && pk[k] == lm) { inclm |= 1 << k; remm &= ~(1 << k); }
        }
        zmaxv = fmaxf((ZFAR_F - zming) / (ZFAR_F - ZNEAR_F), EPS_F);
        #pragma unroll
        for (int k = 0; k < MAXC; ++k)
            if (inclm & (1 << k)) {
                int id = (int)(pk[k] & 0xffffffffull);
                float z = __uint_as_float((unsigned)(pk[k] >> 32));
                AGG(id, z);
            }
    }
#undef AGG

    // ---- wave butterfly reductions (deterministic fixed order) ----
    #pragma unroll
    for (int m = 1; m < 64; m <<= 1) {
        nr += __shfl_xor(nr, m, 64);
        ng += __shfl_xor(ng, m, 64);
        nb += __shfl_xor(nb, m, 64);
        dn += __shfl_xor(dn, m, 64);
        ap *= __shfl_xor(ap, m, 64);
    }
    if (lane == 0) {
        float delta = __expf((EPS_F - zmaxv) / GAMMA_F);
        float dd = dn + delta;
        float4 o4;
        o4.x = (nr + delta) / dd;
        o4.y = (ng + delta) / dd;
        o4.z = (nb + delta) / dd;
        o4.w = 1.0f - ap;
        *reinterpret_cast<float4*>(&out[((size_t)b * NPIX + pi * WW + pj) * 4]) = o4;
    }
}

extern "C" void kernel_launch(void* const* d_in, const int* in_sizes, int n_in,
                              void* d_out, int out_size, void* d_ws, size_t ws_size,
                              hipStream_t stream) {
    const float* mpos   = (const float*)d_in[0];
    const float* mrot   = (const float*)d_in[1];
    const float* mscale = (const float*)d_in[2];
    const float* cpos   = (const float*)d_in[3];
    const float* crot   = (const float*)d_in[4];
    const float* verts  = (const float*)d_in[5];
    const int*   faces  = (const int*)d_in[6];
    const float* vcol   = (const float*)d_in[7];
    float*       out    = (float*)d_out;

    const int B = in_sizes[3] / 3;                  // cam_pos is (B,3)
    dim3 grid(B * NTILE * BPT), block(512);
    render_fused_kernel<<<grid, block, 0, stream>>>(
        mpos, mrot, mscale, cpos, crot, verts, faces, vcol, out);
}